// Round 16
// baseline (412.128 us; speedup 1.0000x reference)
//
#include <hip/hip_runtime.h>
#include <hip/hip_bf16.h>
#include <math.h>

#define EMBED 1024
#define LSEQ 4096
#define BATCH 2
#define ZD 128
#define CHUNKC 2048
#define NSTATE 16
#define DTR 64
#define XDBL_W 96   // DT_RANK + 2*DSTATE
#define NSEG 64
#define TSEG 64     // LSEQ / NSEG

typedef __attribute__((ext_vector_type(8))) short bf16x8;
typedef __attribute__((ext_vector_type(4))) float f32x4;

__device__ __forceinline__ float sigmoidf_(float x){ return 1.f/(1.f+__expf(-x)); }
__device__ __forceinline__ float siluf_(float x){ return x/(1.f+__expf(-x)); }
__device__ __forceinline__ __hip_bfloat16 tobf(float x){ return __float2bfloat16(x); }
__device__ __forceinline__ float frombf(__hip_bfloat16 x){ return __bfloat162float(x); }
__device__ __forceinline__ float frombits(unsigned short u){
  __hip_bfloat16 h; *(unsigned short*)&h = u; return frombf(h);
}
__device__ __forceinline__ short tobits(float x){
  __hip_bfloat16 h = tobf(x); return *(short*)&h;
}

__device__ __forceinline__ void gload_lds16(const void* g, void* l) {
  __builtin_amdgcn_global_load_lds(
      (const __attribute__((address_space(1))) unsigned int*)g,
      (__attribute__((address_space(3))) unsigned int*)l, 16, 0, 0);
}

// ---------------------------------------------------------------- unified prep + rmsnorm:
// [0,1024) v_w->wcat ; [1024,1120) xproj->wcat+1M ; [1120,1152) zero-pad ;
// [1152,2176) h_w->hwb ; [2176,2240) dt_w->dtwb ; [2240,5440) mx_w->mxwb ;
// [5440,5448) gtab ; [5448,13640) rmsnorm rows
__global__ __launch_bounds__(256) void prep_k(
    const float* __restrict__ v_w, const float* __restrict__ xproj_w,
    const float* __restrict__ h_w, const float* __restrict__ dt_w,
    const float* __restrict__ mx_w,
    const float* __restrict__ alpha, const float* __restrict__ beta,
    const float* __restrict__ x, const float* __restrict__ norm_w,
    __hip_bfloat16* __restrict__ wcat, __hip_bfloat16* __restrict__ hwb,
    __hip_bfloat16* __restrict__ dtwb, __hip_bfloat16* __restrict__ mxwb,
    float* __restrict__ gtab, __hip_bfloat16* __restrict__ xnb)
{
  int b = blockIdx.x, tid = threadIdx.x;
  if (b < 5440) {
    const float* s; __hip_bfloat16* d; int idx;
    if (b < 1024)      { idx = (b*256+tid)*4;        s = v_w + idx;      d = wcat + idx; }
    else if (b < 1120) { idx = ((b-1024)*256+tid)*4; s = xproj_w + idx;  d = wcat + (1<<20) + idx; }
    else if (b < 1152) { idx = ((b-1120)*256+tid)*4; s = nullptr;        d = wcat + (1<<20) + 96*1024 + idx; }
    else if (b < 2176) { idx = ((b-1152)*256+tid)*4; s = h_w + idx;      d = hwb + idx; }
    else if (b < 2240) { idx = ((b-2176)*256+tid)*4; s = dt_w + idx;     d = dtwb + idx; }
    else               { idx = ((b-2240)*256+tid)*4; s = mx_w + idx;     d = mxwb + idx; }
    if (s) {
      float4 v = *(const float4*)s;
      d[0]=tobf(v.x); d[1]=tobf(v.y); d[2]=tobf(v.z); d[3]=tobf(v.w);
    } else {
      d[0]=tobf(0.f); d[1]=tobf(0.f); d[2]=tobf(0.f); d[3]=tobf(0.f);
    }
    return;
  }
  if (b < 5448) {
    __shared__ float P[64], Q[64], F[64];
    if (tid < 64) {
      float a1=alpha[tid], a2=alpha[64+tid], b1=beta[tid], b2=beta[64+tid];
      P[tid]=a1*b1+a2*b2;
      Q[tid]=a2*b1-a1*b2;
      F[tid]=expf(-0.14391156831f*(float)tid); // ln(10000)/64
    }
    __syncthreads();
    int d = (b-5440)*256 + tid;
    if (d < CHUNKC) {
      float s=0.f;
      for (int j=0;j<64;++j){
        float th = (float)d * F[j];
        float sn, cs;
        sincosf(th, &sn, &cs);
        s += P[j]*cs - Q[j]*sn;
      }
      gtab[d]=s;
    }
    return;
  }
  // rmsnorm
  size_t row = b - 5448;
  const float* px = x + row*EMBED;
  float4 xv = *(const float4*)(px + tid*4);
  float ss = xv.x*xv.x + xv.y*xv.y + xv.z*xv.z + xv.w*xv.w;
  #pragma unroll
  for (int off=32; off; off>>=1) ss += __shfl_down(ss, off, 64);
  __shared__ float red[4];
  if ((tid&63)==0) red[tid>>6]=ss;
  __syncthreads();
  float tot = red[0]+red[1]+red[2]+red[3];
  float scale = rsqrtf(tot*(1.f/EMBED) + 1e-5f);
  float4 wv = *(const float4*)(norm_w + tid*4);
  __hip_bfloat16* pb = xnb + row*EMBED + tid*4;
  pb[0]=tobf(xv.x*scale*wv.x); pb[1]=tobf(xv.y*scale*wv.y);
  pb[2]=tobf(xv.z*scale*wv.z); pb[3]=tobf(xv.w*scale*wv.w);
}

// ---------------------------------------------------------------- segment-parallel S6 scan
template<bool FINAL>
__global__ __launch_bounds__(256) void seg_scan_k(
    const float* __restrict__ xbc,
    const __hip_bfloat16* __restrict__ dtv,
    const __hip_bfloat16* __restrict__ xnu,
    const float* __restrict__ A_log,
    const float* __restrict__ D_p,
    const float* __restrict__ segInit,
    float* __restrict__ segP,
    float* __restrict__ segH,
    __hip_bfloat16* __restrict__ mx)
{
  int bx = blockIdx.x;
  int seg = bx >> 3;
  int grp = bx & 7;
  int b = grp >> 2;
  int d = (grp & 3)*256 + threadIdx.x;
  int ch = b*EMBED + d;
  int tid = threadIdx.x;
  int tbase = seg*TSEG;

  float A[NSTATE], h[NSTATE], P[NSTATE];
  #pragma unroll
  for (int n=0;n<NSTATE;++n){
    A[n] = -__expf(A_log[(size_t)d*NSTATE+n]);
    P[n] = 1.f;
  }
  if (FINAL) {
    const float* si = segInit + ((size_t)seg*2048 + ch)*NSTATE;
    #pragma unroll
    for (int n=0;n<NSTATE;++n) h[n] = si[n];
  } else {
    #pragma unroll
    for (int n=0;n<NSTATE;++n) h[n] = 0.f;
  }
  float Dp = FINAL ? D_p[d] : 0.f;

  __shared__ float BCb[8][32];
  const float* xd = xbc + ((size_t)b*LSEQ + tbase)*32;
  const __hip_bfloat16* pdt = dtv + ((size_t)b*LSEQ + tbase)*EMBED + d;
  const __hip_bfloat16* pu  = xnu + ((size_t)b*LSEQ + tbase)*EMBED + d;
  __hip_bfloat16* pmx = mx + ((size_t)b*LSEQ + tbase)*EMBED + d;

  for (int t0=0; t0<TSEG; t0+=8) {
    __syncthreads();
    { int tt = tid>>5, jj = tid&31;
      BCb[tt][jj] = xd[(size_t)(t0+tt)*32 + jj]; }
    __syncthreads();
    #pragma unroll
    for (int tt=0; tt<8; ++tt) {
      int t = t0 + tt;
      float dtt = frombf(pdt[(size_t)t*EMBED]);
      float ut  = frombf(pu[(size_t)t*EMBED]);
      float du = dtt*ut;
      float y = 0.f;
      #pragma unroll
      for (int n=0;n<NSTATE;++n){
        float dA = __expf(dtt*A[n]);
        h[n] = dA*h[n] + du*BCb[tt][n];
        if (!FINAL) P[n] *= dA;
        if (FINAL)  y += h[n]*BCb[tt][16+n];
      }
      if (FINAL) pmx[(size_t)t*EMBED] = tobf(siluf_(y + ut*Dp));
    }
  }
  if (!FINAL) {
    float* pp = segP + ((size_t)seg*2048 + ch)*NSTATE;
    float* ph = segH + ((size_t)seg*2048 + ch)*NSTATE;
    #pragma unroll
    for (int n=0;n<NSTATE;n+=4){
      *(float4*)(pp+n) = make_float4(P[n],P[n+1],P[n+2],P[n+3]);
      *(float4*)(ph+n) = make_float4(h[n],h[n+1],h[n+2],h[n+3]);
    }
  }
}

__global__ __launch_bounds__(256) void seg_combine_k(const float* __restrict__ segP,
                                                     const float* __restrict__ segH,
                                                     float* __restrict__ segInit) {
  int idx = blockIdx.x*256 + threadIdx.x;
  float H = 0.f;
  for (int s=0; s<NSEG; ++s) {
    size_t o = (size_t)s*32768 + idx;
    float Pv = segP[o], hl = segH[o];
    segInit[o] = H;
    H = Pv*H + hl;
  }
}

// ---------------------------------------------------------------- row softmax (bf16 in/out), vectorized
__global__ __launch_bounds__(256) void softmax_k(const __hip_bfloat16* __restrict__ S,
                                                 __hip_bfloat16* __restrict__ Sb) {
  size_t row = blockIdx.x;
  const unsigned short* p = (const unsigned short*)(S + row*CHUNKC);
  short* po = (short*)(Sb + row*CHUNKC);
  int tid = threadIdx.x;
  int r = (int)(row & (CHUNKC-1));
  int c0 = tid*8;
  int kcl = ((r >> 7) + 1) << 7;
  float v[8];
  float m = -1e30f;
  if (c0 <= r) {
    bf16x8 raw = *(const bf16x8*)(p + c0);
    #pragma unroll
    for (int i=0;i<8;++i){
      float t = frombits((unsigned short)raw[i]);
      v[i] = (c0 + i <= r) ? t : -1e30f;
      m = fmaxf(m, v[i]);
    }
  } else {
    #pragma unroll
    for (int i=0;i<8;++i) v[i] = -1e30f;
  }
  #pragma unroll
  for (int off=32; off; off>>=1) m = fmaxf(m, __shfl_down(m, off, 64));
  __shared__ float red[4];
  if ((tid&63)==0) red[tid>>6]=m;
  __syncthreads();
  m = fmaxf(fmaxf(red[0],red[1]),fmaxf(red[2],red[3]));
  float s=0.f;
  #pragma unroll
  for (int i=0;i<8;++i){ v[i]=__expf(v[i]-m); s+=v[i]; }
  #pragma unroll
  for (int off=32; off; off>>=1) s += __shfl_down(s, off, 64);
  __syncthreads();
  if ((tid&63)==0) red[tid>>6]=s;
  __syncthreads();
  s = red[0]+red[1]+red[2]+red[3];
  float inv = 1.f/s;
  if (c0 < kcl) {
    bf16x8 o;
    #pragma unroll
    for (int i=0;i<8;++i) o[i] = tobits(v[i]*inv);
    *(bf16x8*)(po + c0) = o;
  }
}

// ---------------------------------------------------------------- bf16 transpose V -> VT[c][n][k]
__global__ __launch_bounds__(256) void transpose_k(const unsigned short* __restrict__ vb,
                                                   unsigned short* __restrict__ VT) {
  __shared__ unsigned short t[64][68];
  int tid = threadIdx.x;
  int tr = tid>>4;
  int tc = (tid&15)*4;
  int c0 = blockIdx.x*64, r0 = blockIdx.y*64;
  #pragma unroll
  for (int it=0; it<4; ++it) {
    int r = it*16 + tr;
    ushort4 v = *(const ushort4*)(vb + (size_t)(r0+r)*EMBED + c0 + tc);
    t[r][tc+0]=v.x; t[r][tc+1]=v.y; t[r][tc+2]=v.z; t[r][tc+3]=v.w;
  }
  __syncthreads();
  int ch = r0 >> 11;
  int kb = r0 & 2047;
  #pragma unroll
  for (int it=0; it<4; ++it) {
    int nl = it*16 + tr;
    ushort4 o;
    o.x = t[tc+0][nl]; o.y = t[tc+1][nl]; o.z = t[tc+2][nl]; o.w = t[tc+3][nl];
    *(ushort4*)(VT + ((size_t)ch*EMBED + c0 + nl)*CHUNKC + kb + tc) = o;
  }
}

// ---------------------------------------------------------------- bf16 MFMA GEMM
// 128x128 tile, BK=64, SINGLE-buffered 32KB LDS, XOR-swizzled staging/reads
// (0 conflicts), bijective XCD swizzle, launch_bounds(256,4).
// PAIR (PV only): block computes row-tiles by and (2*gridDim.y-1-by) sequentially
// -> uniform total K across blocks (TRIK makespan balance).
// EPI: 1 base-split; 2 QK bias+mask->bf16 lower-tri; 3 PV*r->bf16 (TRIK);
//      4 final gate->f32; 6 dt softplus->bf16; 7 v+xdbl merged (compact B/C)
struct MEp {
  const float* bias; const float* gtab; const float* gamma; const float* beta2;
  __hip_bfloat16* ug; __hip_bfloat16* qo; __hip_bfloat16* ko; __hip_bfloat16* ro; __hip_bfloat16* hxo;
  const __hip_bfloat16* rb; const __hip_bfloat16* hxb; const __hip_bfloat16* ub;
  const float* resid; float* outp;
  __hip_bfloat16* Cb; int ldc;
  float* f32o; __hip_bfloat16* bf16o;
};

__device__ __forceinline__ void xcd_swz(int& bx, int& by) {
  const int gx = gridDim.x;
  const int nwg = gx*gridDim.y;
  const int lin = by*gx + bx;
  const int qq = nwg >> 3, rr = nwg & 7;
  const int xcd = lin & 7, pos = lin >> 3;
  const int base = (xcd < rr) ? xcd*(qq+1) : rr*(qq+1) + (xcd-rr)*qq;
  const int lg = base + pos;
  bx = lg % gx; by = lg / gx;
}

#define MBM 128
#define MBK 64

template<int EPI, bool TRIK, bool SWZ, bool PAIR>
__global__ __launch_bounds__(256, 4) void mgemm_k(
    const __hip_bfloat16* __restrict__ A, int lda, long long sAz,
    const __hip_bfloat16* __restrict__ B, int ldb, long long sBz,
    int K, MEp ep)
{
  __shared__ __attribute__((aligned(16))) short As[MBM*MBK];
  __shared__ __attribute__((aligned(16))) short Bs[MBM*MBK];
  const int tid = threadIdx.x;
  const int wv = tid>>6, lane = tid&63;
  const int z = blockIdx.z;
  A += (size_t)z * sAz;
  B += (size_t)z * sBz;
  int bx = blockIdx.x, by = blockIdx.y;
  if constexpr (SWZ) xcd_swz(bx, by);
  const int n0 = bx*MBM;
  const int r8 = lane>>3, g8 = lane&7;
  const int csrc = g8 ^ r8;
  const int wr = wv>>1, wc = wv&1;
  const int fr = lane&15, qv = lane>>4;
  const int x7 = fr & 7;

  const __hip_bfloat16* Bg = B + (size_t)(n0 + wv*32 + r8)*ldb + csrc*8;

  #pragma unroll
  for (int pp = 0; pp < (PAIR ? 2 : 1); ++pp) {
    const int byp = PAIR ? (pp == 0 ? by : (int)(2*gridDim.y) - 1 - by) : by;
    const int m0 = byp*MBM;
    if constexpr (EPI==2) { if (n0 > m0 + (MBM-1)) return; }

    if (pp) __syncthreads();   // pair-1 LDS reads fully done before re-staging

    int Ktot = K;
    if constexpr (TRIK) { int km = m0 + MBM; Ktot = km < K ? km : K; }
    const int nt = Ktot / MBK;

    f32x4 acc[4][4] = {};

    const __hip_bfloat16* Ag = A + (size_t)(m0 + wv*32 + r8)*lda + csrc*8;

    for (int t=0; t<nt; ++t) {
      {
        const int k0 = t*MBK;
        short* Al = &As[wv*32*MBK];
        short* Bl = &Bs[wv*32*MBK];
        #pragma unroll
        for (int j=0;j<4;++j)
          gload_lds16(Ag + (size_t)(j*8)*lda + k0, Al + j*8*MBK);
        #pragma unroll
        for (int j=0;j<4;++j)
          gload_lds16(Bg + (size_t)(j*8)*ldb + k0, Bl + j*8*MBK);
      }
      __syncthreads();                          // drains vmcnt; tile ready on all waves
      #pragma unroll
      for (int kk=0; kk<2; ++kk) {
        const int pos8 = ((kk*4 + qv) ^ x7) * 8;
        bf16x8 af[4], bfr[4];
        #pragma unroll
        for (int mi=0;mi<4;++mi)
          af[mi] = *(const bf16x8*)&As[(wr*64 + mi*16 + fr)*MBK + pos8];
        #pragma unroll
        for (int ni=0;ni<4;++ni)
          bfr[ni] = *(const bf16x8*)&Bs[(wc*64 + ni*16 + fr)*MBK + pos8];
        #pragma unroll
        for (int mi=0;mi<4;++mi)
          #pragma unroll
          for (int ni=0;ni<4;++ni)
            acc[mi][ni] = __builtin_amdgcn_mfma_f32_16x16x32_bf16(af[mi], bfr[ni], acc[mi][ni], 0,0,0);
      }
      if (t+1 < nt) __syncthreads();            // all waves done reading before overwrite
    }

    const int vr = (lane>>4)*4;
    #pragma unroll
    for (int mi=0;mi<4;++mi) {
      #pragma unroll
      for (int v=0; v<4; ++v) {
        const int row = m0 + wr*64 + mi*16 + vr + v;
        #pragma unroll
        for (int ni=0;ni<4;++ni) {
          const int col = n0 + wc*64 + ni*16 + fr;
          float val = acc[mi][ni][v];
          if constexpr (EPI==1) {
            val += ep.bias[col];
            if (col < 1024) {
              ep.ug[(size_t)row*EMBED + col] = tobf(sigmoidf_(val));
            } else if (col < 1152) {
              int jj = col - 1024;
              float zz = siluf_(val);
              ep.qo[(size_t)row*ZD + jj] = tobf((zz*ep.gamma[jj] + ep.beta2[jj]) * 0.08838834764831845f);
              ep.ko[(size_t)row*ZD + jj] = tobf(zz*ep.gamma[128+jj] + ep.beta2[128+jj]);
            } else if (col < 2176) {
              ep.ro[(size_t)row*EMBED + (col-1152)] = tobf(siluf_(val));
            } else {
              ep.hxo[(size_t)row*EMBED + (col-2176)] = tobf(val);
            }
          } else if constexpr (EPI==2) {
            __hip_bfloat16* Sp = ep.Cb + (size_t)z*CHUNKC*CHUNKC;
            if (col <= row) Sp[(size_t)row*CHUNKC + col] = tobf(val + ep.gtab[row-col]);
          } else if constexpr (EPI==3) {
            size_t gr = (size_t)z*CHUNKC + row;
            ep.Cb[gr*EMBED + col] = tobf(val * frombf(ep.rb[gr*EMBED + col]));
          } else if constexpr (EPI==4) {
            float zz = val + ep.bias[col] + frombf(ep.hxb[(size_t)row*EMBED + col]);
            float hh = siluf_(zz);
            float res = ep.resid[(size_t)row*EMBED + col];
            ep.outp[(size_t)row*EMBED + col] = res + frombf(ep.ub[(size_t)row*EMBED + col])*(hh-res);
          } else if constexpr (EPI==6) {
            float zv = val + ep.bias[col];
            ep.bf16o[(size_t)row*EMBED + col] = tobf((zv > 15.f) ? zv : log1pf(__expf(zv)));
          } else {  // EPI==7: v (cols<1024) + xdbl ride-along
            if (col < 1024) {
              ep.Cb[(size_t)row*ep.ldc + col] = tobf(siluf_(val + ep.bias[col]));
            } else {
              int jj = col - 1024;
              if (jj < DTR)          ep.bf16o[(size_t)row*DTR + jj] = tobf(val);
              else if (jj < XDBL_W)  ep.f32o[(size_t)row*32 + (jj - DTR)] = val;
            }
          }
        }
      }
    }
  }
}

// ---------------------------------------------------------------- launch
extern "C" void kernel_launch(void* const* d_in, const int* in_sizes, int n_in,
                              void* d_out, int out_size, void* d_ws, size_t ws_size,
                              hipStream_t stream) {
  const float* x       = (const float*)d_in[0];
  const float* norm_w  = (const float*)d_in[1];
  const float* v_w     = (const float*)d_in[2];
  const float* v_b     = (const float*)d_in[3];
  const float* mx_w    = (const float*)d_in[4];
  const float* mx_b    = (const float*)d_in[5];
  const float* h_w     = (const float*)d_in[6];
  const float* h_b     = (const float*)d_in[7];
  const float* gamma   = (const float*)d_in[8];
  const float* beta    = (const float*)d_in[9];
  const float* alpha_rb= (const float*)d_in[10];
  const float* beta_rb = (const float*)d_in[11];
  const float* xproj_w = (const float*)d_in[12];
  const float* dt_w    = (const float*)d_in[13];
  const float* dt_b    = (const float*)d_in[14];
  const float* A_log   = (const float*)d_in[15];
  const float* D_p     = (const float*)d_in[16];
  float* out = (float*)d_out;

  float* ws = (float*)d_ws;
  size_t off = 0;
  auto alloc = [&](size_t n){ float* p = ws + off; off += n; return p; };
  const size_t BL2 = (size_t)BATCH*LSEQ; // 8192

  float* sbzone  = alloc(BL2*EMBED);        // Sb (bf16 4*2048*2048) lives here
  float* scratch = alloc((size_t)2*CHUNKC*CHUNKC*2); // dtbb+seg*, then S(bf16)
  float* xbc     = alloc(BL2*32);           // compact B/C f32 [row][32]
  float* gtab    = alloc(CHUNKC);
  auto balloc = [&](size_t nbf){ __hip_bfloat16* p = (__hip_bfloat16*)(ws + off); off += (nbf+1)/2; return p; };
  __hip_bfloat16* xnb   = balloc(BL2*EMBED);   // later reused as VT (after scan)
  __hip_bfloat16* vbufb = balloc(BL2*EMBED);
  __hip_bfloat16* mxb   = balloc(BL2*EMBED);
  __hip_bfloat16* qb    = balloc(BL2*ZD);
  __hip_bfloat16* kb    = balloc(BL2*ZD);
  __hip_bfloat16* ugb   = balloc(BL2*EMBED);
  __hip_bfloat16* rbb   = balloc(BL2*EMBED);
  __hip_bfloat16* hxbb  = balloc(BL2*EMBED);
  __hip_bfloat16* hrb   = balloc(BL2*EMBED);
  __hip_bfloat16* xdblb = balloc(BL2*DTR);
  __hip_bfloat16* wcat  = balloc((size_t)1152*EMBED);  // [v_w(1024); xproj_w(96); pad(32)]
  __hip_bfloat16* mxwb  = balloc((size_t)3200*EMBED);
  __hip_bfloat16* hwb   = balloc((size_t)EMBED*EMBED);
  __hip_bfloat16* dtwb  = balloc((size_t)EMBED*DTR);

  __hip_bfloat16* dtbb = (__hip_bfloat16*)scratch;     // bf16 [BL2][EMBED]
  float* segP    = scratch + BL2*EMBED;
  float* segH    = segP + (size_t)NSEG*2048*NSTATE;
  float* segInit = segH + (size_t)NSEG*2048*NSTATE;
  __hip_bfloat16* S  = (__hip_bfloat16*)scratch;  // after scan (bf16 4*2048*2048)
  __hip_bfloat16* Sb = (__hip_bfloat16*)sbzone;   // after scan
  __hip_bfloat16* VT = xnb;                       // after scan pass 3

  // 0. unified prep (weight converts + pad + gtab) + rmsnorm
  prep_k<<<5448 + (int)BL2, 256, 0, stream>>>(v_w, xproj_w, h_w, dt_w, mx_w,
                                              alpha_rb, beta_rb, x, norm_w,
                                              wcat, hwb, dtwb, mxwb, gtab, xnb);

  MEp ep;

  // 1. v = silu(xn @ v_w^T + v_b) [cols<1024] + dt-input bf16 + compact B/C [cols 1024..1119]
  ep = {}; ep.bias = v_b; ep.Cb = vbufb; ep.ldc = EMBED;
  ep.f32o = xbc; ep.bf16o = xdblb;
  mgemm_k<7,false,true,false><<<dim3(1152/MBM, BL2/MBM), 256, 0, stream>>>(
      xnb, EMBED, 0, wcat, EMBED, 0, EMBED, ep);

  // 2. dt = softplus(xdbl[:, :64] @ dt_w^T + dt_b)  (bf16 out)
  ep = {}; ep.bias = dt_b; ep.bf16o = dtbb;
  mgemm_k<6,false,true,false><<<dim3(EMBED/MBM, BL2/MBM), 256, 0, stream>>>(
      xdblb, DTR, 0, dtwb, DTR, 0, DTR, ep);

  // 3. segment-parallel scan -> mxb (reads bf16 dt/u + compact f32 B/C)
  seg_scan_k<false><<<NSEG*8, 256, 0, stream>>>(xbc, dtbb, xnb, A_log, D_p,
                                                nullptr, segP, segH, nullptr);
  seg_combine_k<<<128, 256, 0, stream>>>(segP, segH, segInit);
  seg_scan_k<true><<<NSEG*8, 256, 0, stream>>>(xbc, dtbb, xnb, A_log, D_p,
                                               segInit, nullptr, nullptr, mxb);

  // 3b. transpose V per chunk (xnb dead now -> VT)
  transpose_k<<<dim3(EMBED/64, BL2/64), 256, 0, stream>>>(
      (const unsigned short*)vbufb, (unsigned short*)VT);

  // 4. base = mx @ mx_w^T + mx_b, split epilogue
  ep = {}; ep.bias = mx_b; ep.gamma = gamma; ep.beta2 = beta;
  ep.ug = ugb; ep.qo = qb; ep.ko = kb; ep.ro = rbb; ep.hxo = hxbb;
  mgemm_k<1,false,true,false><<<dim3(3200/MBM, BL2/MBM), 256, 0, stream>>>(
      mxb, EMBED, 0, mxwb, EMBED, 0, EMBED, ep);

  // 5. QK^T + bias + mask -> bf16 S (upper-triangle tiles + stores skipped)
  ep = {}; ep.gtab = gtab; ep.Cb = S;
  mgemm_k<2,false,true,false><<<dim3(CHUNKC/MBM, CHUNKC/MBM, 4), 256, 0, stream>>>(
      qb, ZD, (long long)CHUNKC*ZD, kb, ZD, (long long)CHUNKC*ZD, ZD, ep);

  // 6. softmax (vectorized; causal reads, writes clipped to PV-visible cols)
  softmax_k<<<4*CHUNKC, 256, 0, stream>>>(S, Sb);

  // 7. P@V, K clipped to diagonal, fused *r -> bf16
  //    PAIR: row-tiles (by, 15-by) per block -> uniform K sum = 17*128 per block
  ep = {}; ep.rb = rbb; ep.Cb = hrb;
  mgemm_k<3,true,true,true><<<dim3(EMBED/MBM, CHUNKC/MBM/2, 4), 256, 0, stream>>>(
      Sb, CHUNKC, (long long)CHUNKC*CHUNKC, VT, CHUNKC, (long long)EMBED*CHUNKC, CHUNKC, ep);

  // 8. final: h = silu(hx + (h*r) @ h_w^T + h_b); out = x + u*(h-x)
  ep = {}; ep.bias = h_b; ep.hxb = hxbb; ep.ub = ugb; ep.resid = x; ep.outp = out;
  mgemm_k<4,false,true,false><<<dim3(EMBED/MBM, BL2/MBM), 256, 0, stream>>>(
      hrb, EMBED, 0, hwb, EMBED, 0, EMBED, ep);
}

// Round 17
// 398.639 us; speedup vs baseline: 1.0338x; 1.0338x over previous
//
#include <hip/hip_runtime.h>
#include <hip/hip_bf16.h>
#include <math.h>

#define EMBED 1024
#define LSEQ 4096
#define BATCH 2
#define ZD 128
#define CHUNKC 2048
#define NSTATE 16
#define DTR 64
#define XDBL_W 96   // DT_RANK + 2*DSTATE
#define NSEG 64
#define TSEG 64     // LSEQ / NSEG

typedef __attribute__((ext_vector_type(8))) short bf16x8;
typedef __attribute__((ext_vector_type(4))) float f32x4;

__device__ __forceinline__ float sigmoidf_(float x){ return 1.f/(1.f+__expf(-x)); }
__device__ __forceinline__ float siluf_(float x){ return x/(1.f+__expf(-x)); }
__device__ __forceinline__ __hip_bfloat16 tobf(float x){ return __float2bfloat16(x); }
__device__ __forceinline__ float frombf(__hip_bfloat16 x){ return __bfloat162float(x); }
__device__ __forceinline__ float frombits(unsigned short u){
  __hip_bfloat16 h; *(unsigned short*)&h = u; return frombf(h);
}
__device__ __forceinline__ short tobits(float x){
  __hip_bfloat16 h = tobf(x); return *(short*)&h;
}

__device__ __forceinline__ void gload_lds16(const void* g, void* l) {
  __builtin_amdgcn_global_load_lds(
      (const __attribute__((address_space(1))) unsigned int*)g,
      (__attribute__((address_space(3))) unsigned int*)l, 16, 0, 0);
}

// ---------------------------------------------------------------- unified prep + rmsnorm:
// [0,1024) v_w->wcat ; [1024,1120) xproj->wcat+1M ; [1120,1152) zero-pad ;
// [1152,2176) h_w->hwb ; [2176,2240) dt_w->dtwb ; [2240,5440) mx_w->mxwb ;
// [5440,5448) gtab ; [5448,13640) rmsnorm rows
__global__ __launch_bounds__(256) void prep_k(
    const float* __restrict__ v_w, const float* __restrict__ xproj_w,
    const float* __restrict__ h_w, const float* __restrict__ dt_w,
    const float* __restrict__ mx_w,
    const float* __restrict__ alpha, const float* __restrict__ beta,
    const float* __restrict__ x, const float* __restrict__ norm_w,
    __hip_bfloat16* __restrict__ wcat, __hip_bfloat16* __restrict__ hwb,
    __hip_bfloat16* __restrict__ dtwb, __hip_bfloat16* __restrict__ mxwb,
    float* __restrict__ gtab, __hip_bfloat16* __restrict__ xnb)
{
  int b = blockIdx.x, tid = threadIdx.x;
  if (b < 5440) {
    const float* s; __hip_bfloat16* d; int idx;
    if (b < 1024)      { idx = (b*256+tid)*4;        s = v_w + idx;      d = wcat + idx; }
    else if (b < 1120) { idx = ((b-1024)*256+tid)*4; s = xproj_w + idx;  d = wcat + (1<<20) + idx; }
    else if (b < 1152) { idx = ((b-1120)*256+tid)*4; s = nullptr;        d = wcat + (1<<20) + 96*1024 + idx; }
    else if (b < 2176) { idx = ((b-1152)*256+tid)*4; s = h_w + idx;      d = hwb + idx; }
    else if (b < 2240) { idx = ((b-2176)*256+tid)*4; s = dt_w + idx;     d = dtwb + idx; }
    else               { idx = ((b-2240)*256+tid)*4; s = mx_w + idx;     d = mxwb + idx; }
    if (s) {
      float4 v = *(const float4*)s;
      d[0]=tobf(v.x); d[1]=tobf(v.y); d[2]=tobf(v.z); d[3]=tobf(v.w);
    } else {
      d[0]=tobf(0.f); d[1]=tobf(0.f); d[2]=tobf(0.f); d[3]=tobf(0.f);
    }
    return;
  }
  if (b < 5448) {
    __shared__ float P[64], Q[64], F[64];
    if (tid < 64) {
      float a1=alpha[tid], a2=alpha[64+tid], b1=beta[tid], b2=beta[64+tid];
      P[tid]=a1*b1+a2*b2;
      Q[tid]=a2*b1-a1*b2;
      F[tid]=expf(-0.14391156831f*(float)tid); // ln(10000)/64
    }
    __syncthreads();
    int d = (b-5440)*256 + tid;
    if (d < CHUNKC) {
      float s=0.f;
      for (int j=0;j<64;++j){
        float th = (float)d * F[j];
        float sn, cs;
        sincosf(th, &sn, &cs);
        s += P[j]*cs - Q[j]*sn;
      }
      gtab[d]=s;
    }
    return;
  }
  // rmsnorm
  size_t row = b - 5448;
  const float* px = x + row*EMBED;
  float4 xv = *(const float4*)(px + tid*4);
  float ss = xv.x*xv.x + xv.y*xv.y + xv.z*xv.z + xv.w*xv.w;
  #pragma unroll
  for (int off=32; off; off>>=1) ss += __shfl_down(ss, off, 64);
  __shared__ float red[4];
  if ((tid&63)==0) red[tid>>6]=ss;
  __syncthreads();
  float tot = red[0]+red[1]+red[2]+red[3];
  float scale = rsqrtf(tot*(1.f/EMBED) + 1e-5f);
  float4 wv = *(const float4*)(norm_w + tid*4);
  __hip_bfloat16* pb = xnb + row*EMBED + tid*4;
  pb[0]=tobf(xv.x*scale*wv.x); pb[1]=tobf(xv.y*scale*wv.y);
  pb[2]=tobf(xv.z*scale*wv.z); pb[3]=tobf(xv.w*scale*wv.w);
}

// ---------------------------------------------------------------- segment-parallel S6 scan
template<bool FINAL>
__global__ __launch_bounds__(256) void seg_scan_k(
    const float* __restrict__ xbc,
    const __hip_bfloat16* __restrict__ dtv,
    const __hip_bfloat16* __restrict__ xnu,
    const float* __restrict__ A_log,
    const float* __restrict__ D_p,
    const float* __restrict__ segInit,
    float* __restrict__ segP,
    float* __restrict__ segH,
    __hip_bfloat16* __restrict__ mx)
{
  int bx = blockIdx.x;
  int seg = bx >> 3;
  int grp = bx & 7;
  int b = grp >> 2;
  int d = (grp & 3)*256 + threadIdx.x;
  int ch = b*EMBED + d;
  int tid = threadIdx.x;
  int tbase = seg*TSEG;

  float A[NSTATE], h[NSTATE], P[NSTATE];
  #pragma unroll
  for (int n=0;n<NSTATE;++n){
    A[n] = -__expf(A_log[(size_t)d*NSTATE+n]);
    P[n] = 1.f;
  }
  if (FINAL) {
    const float* si = segInit + ((size_t)seg*2048 + ch)*NSTATE;
    #pragma unroll
    for (int n=0;n<NSTATE;++n) h[n] = si[n];
  } else {
    #pragma unroll
    for (int n=0;n<NSTATE;++n) h[n] = 0.f;
  }
  float Dp = FINAL ? D_p[d] : 0.f;

  __shared__ float BCb[8][32];
  const float* xd = xbc + ((size_t)b*LSEQ + tbase)*32;
  const __hip_bfloat16* pdt = dtv + ((size_t)b*LSEQ + tbase)*EMBED + d;
  const __hip_bfloat16* pu  = xnu + ((size_t)b*LSEQ + tbase)*EMBED + d;
  __hip_bfloat16* pmx = mx + ((size_t)b*LSEQ + tbase)*EMBED + d;

  for (int t0=0; t0<TSEG; t0+=8) {
    __syncthreads();
    { int tt = tid>>5, jj = tid&31;
      BCb[tt][jj] = xd[(size_t)(t0+tt)*32 + jj]; }
    __syncthreads();
    #pragma unroll
    for (int tt=0; tt<8; ++tt) {
      int t = t0 + tt;
      float dtt = frombf(pdt[(size_t)t*EMBED]);
      float ut  = frombf(pu[(size_t)t*EMBED]);
      float du = dtt*ut;
      float y = 0.f;
      #pragma unroll
      for (int n=0;n<NSTATE;++n){
        float dA = __expf(dtt*A[n]);
        h[n] = dA*h[n] + du*BCb[tt][n];
        if (!FINAL) P[n] *= dA;
        if (FINAL)  y += h[n]*BCb[tt][16+n];
      }
      if (FINAL) pmx[(size_t)t*EMBED] = tobf(siluf_(y + ut*Dp));
    }
  }
  if (!FINAL) {
    float* pp = segP + ((size_t)seg*2048 + ch)*NSTATE;
    float* ph = segH + ((size_t)seg*2048 + ch)*NSTATE;
    #pragma unroll
    for (int n=0;n<NSTATE;n+=4){
      *(float4*)(pp+n) = make_float4(P[n],P[n+1],P[n+2],P[n+3]);
      *(float4*)(ph+n) = make_float4(h[n],h[n+1],h[n+2],h[n+3]);
    }
  }
}

__global__ __launch_bounds__(256) void seg_combine_k(const float* __restrict__ segP,
                                                     const float* __restrict__ segH,
                                                     float* __restrict__ segInit) {
  int idx = blockIdx.x*256 + threadIdx.x;
  float H = 0.f;
  for (int s=0; s<NSEG; ++s) {
    size_t o = (size_t)s*32768 + idx;
    float Pv = segP[o], hl = segH[o];
    segInit[o] = H;
    H = Pv*H + hl;
  }
}

// ---------------------------------------------------------------- row softmax (bf16 in/out), vectorized
__global__ __launch_bounds__(256) void softmax_k(const __hip_bfloat16* __restrict__ S,
                                                 __hip_bfloat16* __restrict__ Sb) {
  size_t row = blockIdx.x;
  const unsigned short* p = (const unsigned short*)(S + row*CHUNKC);
  short* po = (short*)(Sb + row*CHUNKC);
  int tid = threadIdx.x;
  int r = (int)(row & (CHUNKC-1));
  int c0 = tid*8;
  int kcl = ((r >> 7) + 1) << 7;
  float v[8];
  float m = -1e30f;
  if (c0 <= r) {
    bf16x8 raw = *(const bf16x8*)(p + c0);
    #pragma unroll
    for (int i=0;i<8;++i){
      float t = frombits((unsigned short)raw[i]);
      v[i] = (c0 + i <= r) ? t : -1e30f;
      m = fmaxf(m, v[i]);
    }
  } else {
    #pragma unroll
    for (int i=0;i<8;++i) v[i] = -1e30f;
  }
  #pragma unroll
  for (int off=32; off; off>>=1) m = fmaxf(m, __shfl_down(m, off, 64));
  __shared__ float red[4];
  if ((tid&63)==0) red[tid>>6]=m;
  __syncthreads();
  m = fmaxf(fmaxf(red[0],red[1]),fmaxf(red[2],red[3]));
  float s=0.f;
  #pragma unroll
  for (int i=0;i<8;++i){ v[i]=__expf(v[i]-m); s+=v[i]; }
  #pragma unroll
  for (int off=32; off; off>>=1) s += __shfl_down(s, off, 64);
  __syncthreads();
  if ((tid&63)==0) red[tid>>6]=s;
  __syncthreads();
  s = red[0]+red[1]+red[2]+red[3];
  float inv = 1.f/s;
  if (c0 < kcl) {
    bf16x8 o;
    #pragma unroll
    for (int i=0;i<8;++i) o[i] = tobits(v[i]*inv);
    *(bf16x8*)(po + c0) = o;
  }
}

// ---------------------------------------------------------------- bf16 transpose V -> VT[c][n][k]
__global__ __launch_bounds__(256) void transpose_k(const unsigned short* __restrict__ vb,
                                                   unsigned short* __restrict__ VT) {
  __shared__ unsigned short t[64][68];
  int tid = threadIdx.x;
  int tr = tid>>4;
  int tc = (tid&15)*4;
  int c0 = blockIdx.x*64, r0 = blockIdx.y*64;
  #pragma unroll
  for (int it=0; it<4; ++it) {
    int r = it*16 + tr;
    ushort4 v = *(const ushort4*)(vb + (size_t)(r0+r)*EMBED + c0 + tc);
    t[r][tc+0]=v.x; t[r][tc+1]=v.y; t[r][tc+2]=v.z; t[r][tc+3]=v.w;
  }
  __syncthreads();
  int ch = r0 >> 11;
  int kb = r0 & 2047;
  #pragma unroll
  for (int it=0; it<4; ++it) {
    int nl = it*16 + tr;
    ushort4 o;
    o.x = t[tc+0][nl]; o.y = t[tc+1][nl]; o.z = t[tc+2][nl]; o.w = t[tc+3][nl];
    *(ushort4*)(VT + ((size_t)ch*EMBED + c0 + nl)*CHUNKC + kb + tc) = o;
  }
}

// ---------------------------------------------------------------- bf16 MFMA GEMM
// 128x128 tile, BK=64, SINGLE-buffered 32KB LDS, XOR-swizzled staging/reads
// (0 conflicts), bijective XCD swizzle, launch_bounds(256,4).
// Best measured config (round 15: 400 us total, base GEMM 93 us / 577 TF).
// Falsified alternatives: BK=32 (slow), double-buffer+counted-vmcnt (flat),
// 256^2 tiles (slow), 4-phase schedule (slow), (256,6) bounds (spills),
// PV row-pairing (overhead, no imbalance existed).
// EPI: 1 base-split; 2 QK bias+mask->bf16 lower-tri; 3 PV*r->bf16 (TRIK);
//      4 final gate->f32; 6 dt softplus->bf16; 7 v+xdbl merged (compact B/C)
struct MEp {
  const float* bias; const float* gtab; const float* gamma; const float* beta2;
  __hip_bfloat16* ug; __hip_bfloat16* qo; __hip_bfloat16* ko; __hip_bfloat16* ro; __hip_bfloat16* hxo;
  const __hip_bfloat16* rb; const __hip_bfloat16* hxb; const __hip_bfloat16* ub;
  const float* resid; float* outp;
  __hip_bfloat16* Cb; int ldc;
  float* f32o; __hip_bfloat16* bf16o;
};

__device__ __forceinline__ void xcd_swz(int& bx, int& by) {
  const int gx = gridDim.x;
  const int nwg = gx*gridDim.y;
  const int lin = by*gx + bx;
  const int qq = nwg >> 3, rr = nwg & 7;
  const int xcd = lin & 7, pos = lin >> 3;
  const int base = (xcd < rr) ? xcd*(qq+1) : rr*(qq+1) + (xcd-rr)*qq;
  const int lg = base + pos;
  bx = lg % gx; by = lg / gx;
}

#define MBM 128
#define MBK 64

template<int EPI, bool TRIK, bool SWZ>
__global__ __launch_bounds__(256, 4) void mgemm_k(
    const __hip_bfloat16* __restrict__ A, int lda, long long sAz,
    const __hip_bfloat16* __restrict__ B, int ldb, long long sBz,
    int K, MEp ep)
{
  __shared__ __attribute__((aligned(16))) short As[MBM*MBK];
  __shared__ __attribute__((aligned(16))) short Bs[MBM*MBK];
  const int tid = threadIdx.x;
  const int wv = tid>>6, lane = tid&63;
  const int z = blockIdx.z;
  A += (size_t)z * sAz;
  B += (size_t)z * sBz;
  int bx = blockIdx.x, by = blockIdx.y;
  if constexpr (SWZ) xcd_swz(bx, by);
  const int m0 = by*MBM, n0 = bx*MBM;
  if constexpr (EPI==2) { if (n0 > m0 + (MBM-1)) return; }
  const int r8 = lane>>3, g8 = lane&7;
  const int csrc = g8 ^ r8;
  const int wr = wv>>1, wc = wv&1;
  const int fr = lane&15, qv = lane>>4;
  const int x7 = fr & 7;

  int Ktot = K;
  if constexpr (TRIK) { int km = m0 + MBM; Ktot = km < K ? km : K; }
  const int nt = Ktot / MBK;

  f32x4 acc[4][4] = {};

  const __hip_bfloat16* Ag = A + (size_t)(m0 + wv*32 + r8)*lda + csrc*8;
  const __hip_bfloat16* Bg = B + (size_t)(n0 + wv*32 + r8)*ldb + csrc*8;

  auto stage = [&](int t){
    const int k0 = t*MBK;
    short* Al = &As[wv*32*MBK];
    short* Bl = &Bs[wv*32*MBK];
    #pragma unroll
    for (int j=0;j<4;++j)
      gload_lds16(Ag + (size_t)(j*8)*lda + k0, Al + j*8*MBK);
    #pragma unroll
    for (int j=0;j<4;++j)
      gload_lds16(Bg + (size_t)(j*8)*ldb + k0, Bl + j*8*MBK);
  };

  for (int t=0; t<nt; ++t) {
    stage(t);
    __syncthreads();                          // drains vmcnt; tile ready on all waves
    #pragma unroll
    for (int kk=0; kk<2; ++kk) {
      const int pos8 = ((kk*4 + qv) ^ x7) * 8;
      bf16x8 af[4], bfr[4];
      #pragma unroll
      for (int mi=0;mi<4;++mi)
        af[mi] = *(const bf16x8*)&As[(wr*64 + mi*16 + fr)*MBK + pos8];
      #pragma unroll
      for (int ni=0;ni<4;++ni)
        bfr[ni] = *(const bf16x8*)&Bs[(wc*64 + ni*16 + fr)*MBK + pos8];
      #pragma unroll
      for (int mi=0;mi<4;++mi)
        #pragma unroll
        for (int ni=0;ni<4;++ni)
          acc[mi][ni] = __builtin_amdgcn_mfma_f32_16x16x32_bf16(af[mi], bfr[ni], acc[mi][ni], 0,0,0);
    }
    if (t+1 < nt) __syncthreads();            // all waves done reading before overwrite
  }

  const int vr = (lane>>4)*4;
  #pragma unroll
  for (int mi=0;mi<4;++mi) {
    #pragma unroll
    for (int v=0; v<4; ++v) {
      const int row = m0 + wr*64 + mi*16 + vr + v;
      #pragma unroll
      for (int ni=0;ni<4;++ni) {
        const int col = n0 + wc*64 + ni*16 + fr;
        float val = acc[mi][ni][v];
        if constexpr (EPI==1) {
          val += ep.bias[col];
          if (col < 1024) {
            ep.ug[(size_t)row*EMBED + col] = tobf(sigmoidf_(val));
          } else if (col < 1152) {
            int jj = col - 1024;
            float zz = siluf_(val);
            ep.qo[(size_t)row*ZD + jj] = tobf((zz*ep.gamma[jj] + ep.beta2[jj]) * 0.08838834764831845f);
            ep.ko[(size_t)row*ZD + jj] = tobf(zz*ep.gamma[128+jj] + ep.beta2[128+jj]);
          } else if (col < 2176) {
            ep.ro[(size_t)row*EMBED + (col-1152)] = tobf(siluf_(val));
          } else {
            ep.hxo[(size_t)row*EMBED + (col-2176)] = tobf(val);
          }
        } else if constexpr (EPI==2) {
          __hip_bfloat16* Sp = ep.Cb + (size_t)z*CHUNKC*CHUNKC;
          if (col <= row) Sp[(size_t)row*CHUNKC + col] = tobf(val + ep.gtab[row-col]);
        } else if constexpr (EPI==3) {
          size_t gr = (size_t)z*CHUNKC + row;
          ep.Cb[gr*EMBED + col] = tobf(val * frombf(ep.rb[gr*EMBED + col]));
        } else if constexpr (EPI==4) {
          float zz = val + ep.bias[col] + frombf(ep.hxb[(size_t)row*EMBED + col]);
          float hh = siluf_(zz);
          float res = ep.resid[(size_t)row*EMBED + col];
          ep.outp[(size_t)row*EMBED + col] = res + frombf(ep.ub[(size_t)row*EMBED + col])*(hh-res);
        } else if constexpr (EPI==6) {
          float zv = val + ep.bias[col];
          ep.bf16o[(size_t)row*EMBED + col] = tobf((zv > 15.f) ? zv : log1pf(__expf(zv)));
        } else {  // EPI==7: v (cols<1024) + xdbl ride-along: dt-input bf16 (64) + compact B/C f32 (32)
          if (col < 1024) {
            ep.Cb[(size_t)row*ep.ldc + col] = tobf(siluf_(val + ep.bias[col]));
          } else {
            int jj = col - 1024;
            if (jj < DTR)          ep.bf16o[(size_t)row*DTR + jj] = tobf(val);
            else if (jj < XDBL_W)  ep.f32o[(size_t)row*32 + (jj - DTR)] = val;
          }
        }
      }
    }
  }
}

// ---------------------------------------------------------------- launch
extern "C" void kernel_launch(void* const* d_in, const int* in_sizes, int n_in,
                              void* d_out, int out_size, void* d_ws, size_t ws_size,
                              hipStream_t stream) {
  const float* x       = (const float*)d_in[0];
  const float* norm_w  = (const float*)d_in[1];
  const float* v_w     = (const float*)d_in[2];
  const float* v_b     = (const float*)d_in[3];
  const float* mx_w    = (const float*)d_in[4];
  const float* mx_b    = (const float*)d_in[5];
  const float* h_w     = (const float*)d_in[6];
  const float* h_b     = (const float*)d_in[7];
  const float* gamma   = (const float*)d_in[8];
  const float* beta    = (const float*)d_in[9];
  const float* alpha_rb= (const float*)d_in[10];
  const float* beta_rb = (const float*)d_in[11];
  const float* xproj_w = (const float*)d_in[12];
  const float* dt_w    = (const float*)d_in[13];
  const float* dt_b    = (const float*)d_in[14];
  const float* A_log   = (const float*)d_in[15];
  const float* D_p     = (const float*)d_in[16];
  float* out = (float*)d_out;

  float* ws = (float*)d_ws;
  size_t off = 0;
  auto alloc = [&](size_t n){ float* p = ws + off; off += n; return p; };
  const size_t BL2 = (size_t)BATCH*LSEQ; // 8192

  float* sbzone  = alloc(BL2*EMBED);        // Sb (bf16 4*2048*2048) lives here
  float* scratch = alloc((size_t)2*CHUNKC*CHUNKC*2); // dtbb+seg*, then S(bf16)
  float* xbc     = alloc(BL2*32);           // compact B/C f32 [row][32]
  float* gtab    = alloc(CHUNKC);
  auto balloc = [&](size_t nbf){ __hip_bfloat16* p = (__hip_bfloat16*)(ws + off); off += (nbf+1)/2; return p; };
  __hip_bfloat16* xnb   = balloc(BL2*EMBED);   // later reused as VT (after scan)
  __hip_bfloat16* vbufb = balloc(BL2*EMBED);
  __hip_bfloat16* mxb   = balloc(BL2*EMBED);
  __hip_bfloat16* qb    = balloc(BL2*ZD);
  __hip_bfloat16* kb    = balloc(BL2*ZD);
  __hip_bfloat16* ugb   = balloc(BL2*EMBED);
  __hip_bfloat16* rbb   = balloc(BL2*EMBED);
  __hip_bfloat16* hxbb  = balloc(BL2*EMBED);
  __hip_bfloat16* hrb   = balloc(BL2*EMBED);
  __hip_bfloat16* xdblb = balloc(BL2*DTR);
  __hip_bfloat16* wcat  = balloc((size_t)1152*EMBED);  // [v_w(1024); xproj_w(96); pad(32)]
  __hip_bfloat16* mxwb  = balloc((size_t)3200*EMBED);
  __hip_bfloat16* hwb   = balloc((size_t)EMBED*EMBED);
  __hip_bfloat16* dtwb  = balloc((size_t)EMBED*DTR);

  __hip_bfloat16* dtbb = (__hip_bfloat16*)scratch;     // bf16 [BL2][EMBED]
  float* segP    = scratch + BL2*EMBED;
  float* segH    = segP + (size_t)NSEG*2048*NSTATE;
  float* segInit = segH + (size_t)NSEG*2048*NSTATE;
  __hip_bfloat16* S  = (__hip_bfloat16*)scratch;  // after scan (bf16 4*2048*2048)
  __hip_bfloat16* Sb = (__hip_bfloat16*)sbzone;   // after scan
  __hip_bfloat16* VT = xnb;                       // after scan pass 3

  // 0. unified prep (weight converts + pad + gtab) + rmsnorm
  prep_k<<<5448 + (int)BL2, 256, 0, stream>>>(v_w, xproj_w, h_w, dt_w, mx_w,
                                              alpha_rb, beta_rb, x, norm_w,
                                              wcat, hwb, dtwb, mxwb, gtab, xnb);

  MEp ep;

  // 1. v = silu(xn @ v_w^T + v_b) [cols<1024] + dt-input bf16 + compact B/C [cols 1024..1119]
  ep = {}; ep.bias = v_b; ep.Cb = vbufb; ep.ldc = EMBED;
  ep.f32o = xbc; ep.bf16o = xdblb;
  mgemm_k<7,false,true><<<dim3(1152/MBM, BL2/MBM), 256, 0, stream>>>(
      xnb, EMBED, 0, wcat, EMBED, 0, EMBED, ep);

  // 2. dt = softplus(xdbl[:, :64] @ dt_w^T + dt_b)  (bf16 out)
  ep = {}; ep.bias = dt_b; ep.bf16o = dtbb;
  mgemm_k<6,false,true><<<dim3(EMBED/MBM, BL2/MBM), 256, 0, stream>>>(
      xdblb, DTR, 0, dtwb, DTR, 0, DTR, ep);

  // 3. segment-parallel scan -> mxb (reads bf16 dt/u + compact f32 B/C)
  seg_scan_k<false><<<NSEG*8, 256, 0, stream>>>(xbc, dtbb, xnb, A_log, D_p,
                                                nullptr, segP, segH, nullptr);
  seg_combine_k<<<128, 256, 0, stream>>>(segP, segH, segInit);
  seg_scan_k<true><<<NSEG*8, 256, 0, stream>>>(xbc, dtbb, xnb, A_log, D_p,
                                               segInit, nullptr, nullptr, mxb);

  // 3b. transpose V per chunk (xnb dead now -> VT)
  transpose_k<<<dim3(EMBED/64, BL2/64), 256, 0, stream>>>(
      (const unsigned short*)vbufb, (unsigned short*)VT);

  // 4. base = mx @ mx_w^T + mx_b, split epilogue
  ep = {}; ep.bias = mx_b; ep.gamma = gamma; ep.beta2 = beta;
  ep.ug = ugb; ep.qo = qb; ep.ko = kb; ep.ro = rbb; ep.hxo = hxbb;
  mgemm_k<1,false,true><<<dim3(3200/MBM, BL2/MBM), 256, 0, stream>>>(
      mxb, EMBED, 0, mxwb, EMBED, 0, EMBED, ep);

  // 5. QK^T + bias + mask -> bf16 S (upper-triangle tiles + stores skipped)
  ep = {}; ep.gtab = gtab; ep.Cb = S;
  mgemm_k<2,false,true><<<dim3(CHUNKC/MBM, CHUNKC/MBM, 4), 256, 0, stream>>>(
      qb, ZD, (long long)CHUNKC*ZD, kb, ZD, (long long)CHUNKC*ZD, ZD, ep);

  // 6. softmax (vectorized; causal reads, writes clipped to PV-visible cols)
  softmax_k<<<4*CHUNKC, 256, 0, stream>>>(S, Sb);

  // 7. P@V, K clipped to diagonal, fused *r -> bf16
  ep = {}; ep.rb = rbb; ep.Cb = hrb;
  mgemm_k<3,true,true><<<dim3(EMBED/MBM, CHUNKC/MBM, 4), 256, 0, stream>>>(
      Sb, CHUNKC, (long long)CHUNKC*CHUNKC, VT, CHUNKC, (long long)EMBED*CHUNKC, CHUNKC, ep);

  // 8. final: h = silu(hx + (h*r) @ h_w^T + h_b); out = x + u*(h-x)
  ep = {}; ep.bias = h_b; ep.hxb = hxbb; ep.ub = ugb; ep.resid = x; ep.outp = out;
  mgemm_k<4,false,true><<<dim3(EMBED/MBM, BL2/MBM), 256, 0, stream>>>(
      hrb, EMBED, 0, hwb, EMBED, 0, EMBED, ep);
}